// Round 12
// baseline (55081.281 us; speedup 1.0000x reference)
//
#include <hip/hip_runtime.h>
#include <cstdint>
#include <cstddef>

#define NB 128
#define NC 16
#define NT 2048
#define NH 256
#define NG 1024
#define NO 10

// workspace layout (bytes)
#define OFF_WQ 0
#define SZ_WQ (NG * NH)             // 262144
#define OFF_SC (OFF_WQ + SZ_WQ)
#define SZ_SC 4096
#define OFF_HB (OFF_SC + SZ_SC)     // hbuf[b][phase][part][128] i8
#define SZ_HB (NB * 2 * 2 * 128)    // 65536
#define OFF_FL (OFF_HB + SZ_HB)     // flags[256], each padded to 128 B
#define SZ_FL (256 * 128)           // 32768
#define OFF_HF (OFF_FL + SZ_FL)     // hfinal[b][128] f32 (full-precision h_T)
#define SZ_HF (NB * 128 * 4)        // 65536
#define WS_NEED (OFF_HF + SZ_HF)    // 430080

typedef _Float16 f16;
typedef _Float16 h2 __attribute__((ext_vector_type(2)));
typedef _Float16 h8 __attribute__((ext_vector_type(8)));

static __device__ __forceinline__ float fdot2(h2 a, h2 b, float c) {
#if __has_builtin(__builtin_amdgcn_fdot2)
  return __builtin_amdgcn_fdot2(a, b, c, false);
#else
  return c + (float)a[0] * (float)b[0] + (float)a[1] * (float)b[1];
#endif
}

static __device__ __forceinline__ int sdot4(int a, int b, int c) {
#if __has_builtin(__builtin_amdgcn_sdot4)
  return __builtin_amdgcn_sdot4(a, b, c, false);
#else
  int r = c;
#pragma unroll
  for (int i = 0; i < 4; ++i)
    r += (int)(int8_t)(a >> (8 * i)) * (int)(int8_t)(b >> (8 * i));
  return r;
#endif
}

// DPP lane swaps (no DS traffic). pairswap: 2k<->2k+1. quadswap: +-2.
static __device__ __forceinline__ float pairswap(float v) {
  int r = __builtin_amdgcn_update_dpp(0, __builtin_bit_cast(int, v),
                                      0xB1, 0xF, 0xF, true);
  return __builtin_bit_cast(float, r);
}
static __device__ __forceinline__ float quadswap(float v) {
  int r = __builtin_amdgcn_update_dpp(0, __builtin_bit_cast(int, v),
                                      0x4E, 0xF, 0xF, true);  // quad_perm [2,3,0,1]
  return __builtin_bit_cast(float, r);
}

static __device__ __forceinline__ float sigm(float x) {
  return __builtin_amdgcn_rcpf(1.f + __expf(-x));
}
static __device__ __forceinline__ float tanh_(float x) {
  return 1.f - 2.f * __builtin_amdgcn_rcpf(1.f + __expf(2.f * x));
}

// Quantize w_hh to i8 (per-row scale). Block 0 additionally zeroes the
// pair-exchange region (hbuf+flags+hfinal) so every launch/replay starts
// with clean flags (stream order guarantees completion before lstm_pair).
__global__ void prepack_whh_i8(const float* __restrict__ whh,
                               int8_t* __restrict__ wq,
                               float* __restrict__ scale,
                               int* __restrict__ zbase, int zwords) {
  int row = blockIdx.x;
  int k = threadIdx.x;
  if (row == 0 && zbase) {
    for (int i = k; i < zwords; i += NH) zbase[i] = 0;
  }
  float v = whh[row * NH + k];
  float m = fabsf(v);
  for (int off = 32; off; off >>= 1) m = fmaxf(m, __shfl_xor(m, off, 64));
  __shared__ float smax[4];
  if ((k & 63) == 0) smax[k >> 6] = m;
  __syncthreads();
  float mm = fmaxf(fmaxf(smax[0], smax[1]), fmaxf(smax[2], smax[3]));
  float s = fmaxf(mm, 1e-20f) / 127.f;
  int qv = (int)rintf(v / s);
  qv = min(127, max(-127, qv));
  wq[row * NH + k] = (int8_t)qv;
  if (k == 0) scale[row] = s;
}

// PAIRED-WG LSTM: 256 WGs (one per CU), pair (b, b+128) shares batch b
// (same XCD under round-robin dispatch: 128 % 8 == 0). WG part P owns
// units [128P, 128P+128). 4 lanes/unit, each lane covers 32 local +
// 32 remote k-bytes -> 64 sdot4/step (half of the 1-WG kernel).
// Per-step h exchange: own 128-B half -> global hbuf[b][phase][P] via
// wave-0 agent-scope atomic stores, then release flag=s+1; reader spins
// partner>=s (acquire), reads remote half with agent-scope atomic loads
// (L1-bypassing, XCD-safe). Protocol: flag s implies partner finished
// reading buffer[(s+1)&1] (its step s-1 input), so overwriting is safe.
// Head: P1 publishes full-precision h_T (f32) once; P0 computes logits.
__global__ __launch_bounds__(512, 2)
void lstm_pair(const float* __restrict__ x, const float* __restrict__ w_ih,
               const float* __restrict__ b_ih, const float* __restrict__ b_hh,
               const float* __restrict__ w_out, const float* __restrict__ b_out,
               const int8_t* __restrict__ wq, const float* __restrict__ scales,
               int8_t* __restrict__ hbuf, int* __restrict__ flags,
               float* __restrict__ hfinal, float* __restrict__ out) {
  const int t = threadIdx.x;   // 0..511
  const int wg = blockIdx.x;   // 0..255
  const int b = wg & (NB - 1);
  const int P = wg >> 7;       // part 0/1
  const int uL = t >> 2;       // local unit 0..127
  const int q = t & 3;         // k-slice
  const int ug = P * 128 + uL; // global unit

  int8_t* hb_b = hbuf + (size_t)b * 512;  // [phase][part][128]
  int* myflag = flags + wg * 32;
  int* paflag = flags + (wg ^ 128) * 32;

  __shared__ __align__(16) int8_t hql[2][128];  // own-half h, 2 phases
  __shared__ __align__(16) f16 xs[64][NC];
  __shared__ float hT[NH];
  __shared__ float lg[NO];

  // ---------------- one-time loads ----------------
  // lane k-coverage: local bytes [128P+32q, +32), remote [128(1-P)+32q, +32)
  int wl[4][8], wr[4][8];
  h2 wihq[4][2];
  float sc[4], bb[4];
#pragma unroll
  for (int gt = 0; gt < 4; ++gt) {
    const int8_t* row = wq + (size_t)(256 * gt + ug) * NH;
    const int4* pl = (const int4*)(row + 128 * P + 32 * q);
    const int4* pr = (const int4*)(row + 128 * (1 - P) + 32 * q);
    int4 a0 = pl[0], a1 = pl[1], r0 = pr[0], r1 = pr[1];
    wl[gt][0] = a0.x; wl[gt][1] = a0.y; wl[gt][2] = a0.z; wl[gt][3] = a0.w;
    wl[gt][4] = a1.x; wl[gt][5] = a1.y; wl[gt][6] = a1.z; wl[gt][7] = a1.w;
    wr[gt][0] = r0.x; wr[gt][1] = r0.y; wr[gt][2] = r0.z; wr[gt][3] = r0.w;
    wr[gt][4] = r1.x; wr[gt][5] = r1.y; wr[gt][6] = r1.z; wr[gt][7] = r1.w;
    const float* wi = w_ih + (size_t)(256 * gt + ug) * NC + 4 * q;
    h2 w0 = {(f16)wi[0], (f16)wi[1]};
    h2 w1 = {(f16)wi[2], (f16)wi[3]};
    wihq[gt][0] = w0;
    wihq[gt][1] = w1;
    sc[gt] = scales[256 * gt + ug] * (1.f / 127.f);
    bb[gt] = (q == 0) ? (b_ih[256 * gt + ug] + b_hh[256 * gt + ug]) : 0.f;
  }

  if (t < 128) hql[0][t] = 0;
  else if (t < 256) hql[1][t - 128] = 0;
#pragma unroll
  for (int r = 0; r < 2; ++r) {
    int e = t + 512 * r;
    int cc = e >> 6, tt = e & 63;
    xs[tt][cc] = (f16)x[(size_t)(b * NC + cc) * NT + tt];
  }
  __syncthreads();

  // ---------------- recurrence ----------------
  float c_ = 0.f, h_last = 0.f;

#pragma unroll 1
  for (int s = 0; s < NT; ++s) {
    const int p = s & 1;
    const int pn = p ^ 1;

    // wait for partner's h(s) half (step 0: flags pre-zeroed, no wait)
    if (s > 0) {
      while (__hip_atomic_load(paflag, __ATOMIC_ACQUIRE,
                               __HIP_MEMORY_SCOPE_AGENT) < s)
        __builtin_amdgcn_s_sleep(1);
    }

    // remote 32 h-bytes (agent-scope loads: L1-bypassing, coherent)
    const int* rw = (const int*)(hb_b + p * 256 + (1 - P) * 128 + 32 * q);
    int rh[8];
#pragma unroll
    for (int j = 0; j < 8; ++j)
      rh[j] = __hip_atomic_load(rw + j, __ATOMIC_RELAXED,
                                __HIP_MEMORY_SCOPE_AGENT);

    // local 32 h-bytes (LDS, 4 broadcast addrs/wave)
    const int4* lw = (const int4*)(hql[p] + 32 * q);
    int4 l0 = lw[0], l1 = lw[1];

    // x-projection partial: channels 4q..4q+3
    h2 xa = *(const h2*)&xs[s & 63][4 * q];
    h2 xb = *(const h2*)&xs[s & 63][4 * q + 2];

    float gv[4];
#pragma unroll
    for (int gt = 0; gt < 4; ++gt) {
      float fx = bb[gt];
      fx = fdot2(xa, wihq[gt][0], fx);
      fx = fdot2(xb, wihq[gt][1], fx);
      int a = 0;
      a = sdot4(l0.x, wl[gt][0], a); a = sdot4(l0.y, wl[gt][1], a);
      a = sdot4(l0.z, wl[gt][2], a); a = sdot4(l0.w, wl[gt][3], a);
      a = sdot4(l1.x, wl[gt][4], a); a = sdot4(l1.y, wl[gt][5], a);
      a = sdot4(l1.z, wl[gt][6], a); a = sdot4(l1.w, wl[gt][7], a);
#pragma unroll
      for (int j = 0; j < 8; ++j) a = sdot4(rh[j], wr[gt][j], a);
      // dequant partial, then 4-lane reduce (XOR1 then XOR2)
      float v = fx + (float)a * sc[gt];
      v += pairswap(v);
      v += quadswap(v);
      gv[gt] = v;
    }

    float ig = sigm(gv[0]);
    float fg = sigm(gv[1]);
    float gg = tanh_(gv[2]);
    float og = sigm(gv[3]);
    c_ = fg * c_ + ig * gg;
    float hh = og * tanh_(c_);
    h_last = hh;
    if (q == 0) hql[pn][uL] = (int8_t)(int)rintf(hh * 127.f);

    __syncthreads();

    // publish own h(s+1) half; wave 0 only, so t0's release covers all
    if (t < 32) {
      int wv = ((const int*)hql[pn])[t];
      __hip_atomic_store((int*)(hb_b + pn * 256 + P * 128) + t, wv,
                         __ATOMIC_RELAXED, __HIP_MEMORY_SCOPE_AGENT);
    }
    if (t == 0)
      __hip_atomic_store(myflag, s + 1, __ATOMIC_RELEASE,
                         __HIP_MEMORY_SCOPE_AGENT);

    // restage x every 64 steps (reads of step s all before barrier above)
    if ((s & 63) == 63 && s != NT - 1) {
#pragma unroll
      for (int r = 0; r < 2; ++r) {
        int e = t + 512 * r;
        int cc = e >> 6, tt = e & 63;
        xs[tt][cc] = (f16)x[(size_t)(b * NC + cc) * NT + (s + 1) + tt];
      }
      __syncthreads();
    }
  }

  // ---------------- head ----------------
  if (P == 1) {
    // publish full-precision h_T half once (through LDS, wave-0 stores)
    if (q == 0) hT[uL] = h_last;
    __syncthreads();
    if (t < 64) {
      int* dst = (int*)(hfinal + (size_t)b * 128);
      __hip_atomic_store(dst + 2 * t, __builtin_bit_cast(int, hT[2 * t]),
                         __ATOMIC_RELAXED, __HIP_MEMORY_SCOPE_AGENT);
      __hip_atomic_store(dst + 2 * t + 1, __builtin_bit_cast(int, hT[2 * t + 1]),
                         __ATOMIC_RELAXED, __HIP_MEMORY_SCOPE_AGENT);
    }
    if (t == 0)
      __hip_atomic_store(myflag, NT + 1, __ATOMIC_RELEASE,
                         __HIP_MEMORY_SCOPE_AGENT);
  } else {
    if (q == 0) hT[uL] = h_last;
    while (__hip_atomic_load(paflag, __ATOMIC_ACQUIRE,
                             __HIP_MEMORY_SCOPE_AGENT) < NT + 1)
      __builtin_amdgcn_s_sleep(1);
    if (t < 128) {
      int v = __hip_atomic_load((const int*)(hfinal + (size_t)b * 128) + t,
                                __ATOMIC_RELAXED, __HIP_MEMORY_SCOPE_AGENT);
      hT[128 + t] = __builtin_bit_cast(float, v);
    }
    __syncthreads();
    if (t < NO) {
      float acc = b_out[t];
      for (int k = 0; k < NH; ++k) acc += hT[k] * w_out[t * NH + k];
      lg[t] = acc;
    }
    __syncthreads();
    if (t == 0) {
      float m = lg[0];
      for (int o = 1; o < NO; ++o) m = fmaxf(m, lg[o]);
      float ssum = 0.f;
      for (int o = 0; o < NO; ++o) ssum += __expf(lg[o] - m);
      float lse = m + __logf(ssum);
      for (int o = 0; o < NO; ++o) out[b * NO + o] = lg[o] - lse;
    }
  }
}

// ---------- fallback: round-9 single-WG kernel (1822 us, verified) ----------
__global__ __launch_bounds__(512, 2)
void lstm_main(const float* __restrict__ x, const float* __restrict__ w_ih,
               const float* __restrict__ b_ih, const float* __restrict__ b_hh,
               const float* __restrict__ w_out, const float* __restrict__ b_out,
               const int8_t* __restrict__ wq, const float* __restrict__ scales,
               float* __restrict__ out) {
  const int t = threadIdx.x;
  const int u = t >> 1;
  const int half = t & 1;
  const int b = blockIdx.x;

  __shared__ __align__(16) int8_t hq[2][NH];
  __shared__ __align__(16) f16 xs[64][NC];
  __shared__ float hT[NH];
  __shared__ float lg[NO];

  int wi_[32], wf_[32], wg_[32], wo_[32];
  {
    const int4* pi = (const int4*)(wq + (size_t)u * NH + 128 * half);
    const int4* pf = (const int4*)(wq + (size_t)(256 + u) * NH + 128 * half);
    const int4* pg = (const int4*)(wq + (size_t)(512 + u) * NH + 128 * half);
    const int4* po = (const int4*)(wq + (size_t)(768 + u) * NH + 128 * half);
#pragma unroll
    for (int c = 0; c < 8; ++c) {
      int4 vi = pi[c], vf = pf[c], vg = pg[c], vo = po[c];
      wi_[4 * c + 0] = vi.x; wi_[4 * c + 1] = vi.y; wi_[4 * c + 2] = vi.z; wi_[4 * c + 3] = vi.w;
      wf_[4 * c + 0] = vf.x; wf_[4 * c + 1] = vf.y; wf_[4 * c + 2] = vf.z; wf_[4 * c + 3] = vf.w;
      wg_[4 * c + 0] = vg.x; wg_[4 * c + 1] = vg.y; wg_[4 * c + 2] = vg.z; wg_[4 * c + 3] = vg.w;
      wo_[4 * c + 0] = vo.x; wo_[4 * c + 1] = vo.y; wo_[4 * c + 2] = vo.z; wo_[4 * c + 3] = vo.w;
    }
  }
  h2 wih[4][4];
#pragma unroll
  for (int g4 = 0; g4 < 4; ++g4) {
    int row = u + 256 * g4;
#pragma unroll
    for (int uu = 0; uu < 4; ++uu) {
      h2 t2 = {(f16)w_ih[row * NC + 8 * half + 2 * uu],
               (f16)w_ih[row * NC + 8 * half + 2 * uu + 1]};
      wih[g4][uu] = t2;
    }
  }
  const float K = 1.f / 127.f;
  float sci = scales[u] * K, scf = scales[256 + u] * K;
  float scg = scales[512 + u] * K, sco = scales[768 + u] * K;
  float bi_ = half ? 0.f : b_ih[u] + b_hh[u];
  float bf_ = half ? 0.f : b_ih[256 + u] + b_hh[256 + u];
  float bg_ = half ? 0.f : b_ih[512 + u] + b_hh[512 + u];
  float bo_ = half ? 0.f : b_ih[768 + u] + b_hh[768 + u];

  ((int8_t*)hq)[t] = 0;
#pragma unroll
  for (int r = 0; r < 2; ++r) {
    int e = t + 512 * r;
    int cc = e >> 6, tt = e & 63;
    xs[tt][cc] = (f16)x[(size_t)(b * NC + cc) * NT + tt];
  }
  __syncthreads();

  float c_ = 0.f, h_last = 0.f;
#pragma unroll 1
  for (int s = 0; s < NT; ++s) {
    const int p = s & 1;
    const int4* hrd = (const int4*)(hq[p] + 128 * half);
    float fi = bi_, ff = bf_, fg_ = bg_, fo = bo_;
    {
      h8 xv = *(const h8*)&xs[s & 63][8 * half];
#pragma unroll
      for (int uu = 0; uu < 4; ++uu) {
        h2 xp = {xv[2 * uu], xv[2 * uu + 1]};
        fi = fdot2(xp, wih[0][uu], fi);
        ff = fdot2(xp, wih[1][uu], ff);
        fg_ = fdot2(xp, wih[2][uu], fg_);
        fo = fdot2(xp, wih[3][uu], fo);
      }
    }
    int ai = 0, af = 0, ag = 0, ao = 0;
#pragma unroll
    for (int c = 0; c < 8; ++c) {
      int4 hv = hrd[c];
      ai = sdot4(hv.x, wi_[4 * c + 0], ai); ai = sdot4(hv.y, wi_[4 * c + 1], ai);
      ai = sdot4(hv.z, wi_[4 * c + 2], ai); ai = sdot4(hv.w, wi_[4 * c + 3], ai);
      af = sdot4(hv.x, wf_[4 * c + 0], af); af = sdot4(hv.y, wf_[4 * c + 1], af);
      af = sdot4(hv.z, wf_[4 * c + 2], af); af = sdot4(hv.w, wf_[4 * c + 3], af);
      ag = sdot4(hv.x, wg_[4 * c + 0], ag); ag = sdot4(hv.y, wg_[4 * c + 1], ag);
      ag = sdot4(hv.z, wg_[4 * c + 2], ag); ag = sdot4(hv.w, wg_[4 * c + 3], ag);
      ao = sdot4(hv.x, wo_[4 * c + 0], ao); ao = sdot4(hv.y, wo_[4 * c + 1], ao);
      ao = sdot4(hv.z, wo_[4 * c + 2], ao); ao = sdot4(hv.w, wo_[4 * c + 3], ao);
    }
    float vi = fi + (float)ai * sci;
    float vf = ff + (float)af * scf;
    float vg = fg_ + (float)ag * scg;
    float vo = fo + (float)ao * sco;
    vi += pairswap(vi); vf += pairswap(vf); vg += pairswap(vg); vo += pairswap(vo);
    float ig = sigm(vi), fgate = sigm(vf), gv = tanh_(vg), og = sigm(vo);
    c_ = fgate * c_ + ig * gv;
    float hh = og * tanh_(c_);
    h_last = hh;
    if (!half) hq[1 - p][u] = (int8_t)(int)rintf(hh * 127.f);
    if ((s & 63) == 63 && s != NT - 1) {
      __syncthreads();
#pragma unroll
      for (int r = 0; r < 2; ++r) {
        int e = t + 512 * r;
        int cc = e >> 6, tt = e & 63;
        xs[tt][cc] = (f16)x[(size_t)(b * NC + cc) * NT + (s + 1) + tt];
      }
    }
    __syncthreads();
  }

  if (!half) hT[u] = h_last;
  __syncthreads();
  if (t < NO) {
    float acc = b_out[t];
    for (int k = 0; k < NH; ++k) acc += hT[k] * w_out[t * NH + k];
    lg[t] = acc;
  }
  __syncthreads();
  if (t == 0) {
    float m = lg[0];
    for (int o = 1; o < NO; ++o) m = fmaxf(m, lg[o]);
    float ssum = 0.f;
    for (int o = 0; o < NO; ++o) ssum += __expf(lg[o] - m);
    float lse = m + __logf(ssum);
    for (int o = 0; o < NO; ++o) out[b * NO + o] = lg[o] - lse;
  }
}

extern "C" void kernel_launch(void* const* d_in, const int* in_sizes, int n_in,
                              void* d_out, int out_size, void* d_ws, size_t ws_size,
                              hipStream_t stream) {
  const float* x    = (const float*)d_in[0];
  const float* wih  = (const float*)d_in[1];
  const float* whh  = (const float*)d_in[2];
  const float* bih  = (const float*)d_in[3];
  const float* bhh  = (const float*)d_in[4];
  const float* wout = (const float*)d_in[5];
  const float* bout = (const float*)d_in[6];
  float* out = (float*)d_out;
  int8_t* wq = (int8_t*)d_ws;
  float* scales = (float*)((char*)d_ws + OFF_SC);

  const bool pair = ws_size >= (size_t)WS_NEED;
  int* zbase = pair ? (int*)((char*)d_ws + OFF_HB) : nullptr;
  int zwords = pair ? (SZ_HB + SZ_FL + SZ_HF) / 4 : 0;

  hipLaunchKernelGGL(prepack_whh_i8, dim3(NG), dim3(NH), 0, stream,
                     whh, wq, scales, zbase, zwords);
  if (pair) {
    int8_t* hbuf = (int8_t*)((char*)d_ws + OFF_HB);
    int* flags = (int*)((char*)d_ws + OFF_FL);
    float* hfinal = (float*)((char*)d_ws + OFF_HF);
    hipLaunchKernelGGL(lstm_pair, dim3(2 * NB), dim3(512), 0, stream,
                       x, wih, bih, bhh, wout, bout,
                       (const int8_t*)wq, (const float*)scales,
                       hbuf, flags, hfinal, out);
  } else {
    hipLaunchKernelGGL(lstm_main, dim3(NB), dim3(512), 0, stream,
                       x, wih, bih, bhh, wout, bout,
                       (const int8_t*)wq, (const float*)scales, out);
  }
}